// Round 6
// baseline (492.670 us; speedup 1.0000x reference)
//
#include <hip/hip_runtime.h>
#include <hip/hip_bf16.h>

// XLNet rel-attn layer + FFN. Round 6: attention K/V global->register (V^T
// produced by GEMM), KR double-buffered LDS, ONE barrier per tile; merged
// prep kernel; kr proj TM=128.
// QLEN=1024 MLEN=1024 BSZ=2 DM=1024 NH=16 DH=64 DI=4096 KLEN=2048 RLEN=3072.

#define QLEN 1024
#define MLEN 1024
#define DM 1024
#define NH 16
#define DH 64
#define DI 4096
#define KLEN 2048
#define RLEN 3072

typedef __attribute__((ext_vector_type(8))) short s16x8;
typedef __attribute__((ext_vector_type(4))) float f32x4;
typedef unsigned short us;

__device__ __forceinline__ float bf2f(us u) {
    union { unsigned int i; float f; } x; x.i = ((unsigned int)u) << 16; return x.f;
}
__device__ __forceinline__ us f2bf(float f) {
    union { float f; unsigned int i; } x; x.f = f;
    return (us)((x.i + 0x7fffu + ((x.i >> 16) & 1u)) >> 16);
}
__device__ __forceinline__ void gload16(const void* g, void* lds) {
    __builtin_amdgcn_global_load_lds(
        (const __attribute__((address_space(1))) unsigned int*)g,
        (__attribute__((address_space(3))) unsigned int*)lds, 16, 0, 0);
}

// ---------------- block reduction (wave=64, 4 waves/block) ------------------
template<bool ISMAX>
__device__ __forceinline__ float block_reduce(float v, float* red, int t) {
    #pragma unroll
    for (int off = 32; off > 0; off >>= 1) {
        float o = __shfl_down(v, off);
        v = ISMAX ? fmaxf(v, o) : (v + o);
    }
    if ((t & 63) == 0) red[t >> 6] = v;
    __syncthreads();
    if (t == 0) {
        float s = red[0];
        #pragma unroll
        for (int w = 1; w < 4; ++w) s = ISMAX ? fmaxf(s, red[w]) : (s + red[w]);
        red[4] = s;
    }
    __syncthreads();
    return red[4];
}

// ---------------- unified prep: all fp32->bf16 converts + transposes --------
// blocks [0,5632): vector converts (mems,h -> cat_bf; r -> r_bf; wo -> wo_b)
// blocks [5632,6656): wq,wk,wv,wr transposes (256 tiles each)
// blocks [6656,7680): w1 transpose; [7680,8704): w2 transpose
__global__ __launch_bounds__(256) void prep_k(
    const float* __restrict__ mems, const float* __restrict__ h,
    const float* __restrict__ r, const float* __restrict__ wo,
    const float* __restrict__ wq, const float* __restrict__ wk,
    const float* __restrict__ wv, const float* __restrict__ wr,
    const float* __restrict__ w1, const float* __restrict__ w2,
    us* __restrict__ cat_bf, us* __restrict__ r_bf, us* __restrict__ wo_b,
    us* __restrict__ wqk_t, us* __restrict__ wv_t, us* __restrict__ wr_t,
    us* __restrict__ w1_t, us* __restrict__ w2_t)
{
    __shared__ us tbuf[64][65];
    int bid = blockIdx.x;
    const int tid = threadIdx.x;
    if (bid < 5632) {
        int t = bid * 256 + tid;
        const float* src; us* dst; int off;
        if (t < 262144)       { src = mems; dst = cat_bf;           off = t; }
        else if (t < 524288)  { src = h;    dst = cat_bf + 2097152; off = t - 262144; }
        else if (t < 1310720) { src = r;    dst = r_bf;             off = t - 524288; }
        else                  { src = wo;   dst = wo_b;             off = t - 1310720; }
        const float4* p = (const float4*)src + 2 * (size_t)off;
        float4 a = p[0], b = p[1];
        us o[8] = { f2bf(a.x), f2bf(a.y), f2bf(a.z), f2bf(a.w),
                    f2bf(b.x), f2bf(b.y), f2bf(b.z), f2bf(b.w) };
        *((uint4*)dst + off) = *(const uint4*)o;
        return;
    }
    bid -= 5632;
    const float* in; us* out; int R, C, c0, r0;
    if (bid < 1024) {
        int z = bid >> 8, u = bid & 255;
        in  = (z == 0) ? wq : (z == 1) ? wk : (z == 2) ? wv : wr;
        out = (z == 0) ? wqk_t : (z == 1) ? (wqk_t + 1048576) : (z == 2) ? wv_t : wr_t;
        R = 1024; C = 1024; c0 = (u & 15) * 64; r0 = (u >> 4) * 64;
    } else if (bid < 2048) {
        int u = bid - 1024;
        in = w1; out = w1_t; R = 1024; C = 4096;
        c0 = (u & 63) * 64; r0 = (u >> 6) * 64;
    } else {
        int u = bid - 2048;
        in = w2; out = w2_t; R = 4096; C = 1024;
        c0 = (u & 15) * 64; r0 = (u >> 4) * 64;
    }
    #pragma unroll
    for (int u = 0; u < 16; ++u) {
        int idx = tid + 256 * u;
        int rr = idx >> 6, cc = idx & 63;
        tbuf[cc][rr] = f2bf(in[(size_t)(r0 + rr) * C + c0 + cc]);
    }
    __syncthreads();
    #pragma unroll
    for (int u = 0; u < 16; ++u) {
        int idx = tid + 256 * u;
        int rr = idx >> 6, cc = idx & 63;
        out[(size_t)(c0 + rr) * R + r0 + cc] = tbuf[rr][cc];
    }
}

// ---------------- pipelined bf16 MFMA GEMM ----------------------------------
// C[M,N] = A[M,K] @ Bt[N,K]^T. Tile TM x 128, BK=32, dbuf LDS, counted vmcnt,
// XCD swizzle, split-K via blockIdx.z.
// EPI: 0 f32; 1 bias+gelu->bf16; 2 bias(z0)->f32; 3 bf16 scatter [bn][seq][64];
//      4 qk scatter; 5 v^T scatter [bn][d][j].
template<int TM, int EPI>
__global__ __launch_bounds__(256) void gemm2(
    const us* __restrict__ A, const us* __restrict__ Bt,
    const float* __restrict__ bias, void* __restrict__ Cout,
    int M, int N, int K, int kchunk, size_t zstride)
{
    constexpr int MF = TM / 32;
    constexpr int AISS = TM / 64;
    __shared__ us As[2][TM * 32];
    __shared__ us Bs[2][128 * 32];

    const int tid = threadIdx.x;
    const int w = tid >> 6, l = tid & 63;
    const int lm = l & 15, lg = l >> 4;

    int lin = blockIdx.y * gridDim.x + blockIdx.x;
    int nwg = gridDim.x * gridDim.y;
    int swz = (lin & 7) * (nwg >> 3) + (lin >> 3);
    int bx = swz % gridDim.x, by = swz / gridDim.x;
    const int m0 = by * TM, n0 = bx * 128;
    const int wr = (w >> 1) * (TM / 2), wc = (w & 1) * 64;
    const int kbeg = blockIdx.z * kchunk;
    const int nt = kchunk / 32;

    f32x4 acc[MF][4] = {};

    auto stage = [&](int buf, int k0) {
        #pragma unroll
        for (int u = 0; u < AISS; ++u) {
            int c = (u * 4 + w) * 64 + l;
            int row = c & (TM - 1), kc = c >> (TM == 128 ? 7 : 6);
            gload16(A + (size_t)(m0 + row) * K + k0 + kc * 8,
                    &As[buf][(u * 4 + w) * 512]);
        }
        #pragma unroll
        for (int u = 0; u < 2; ++u) {
            int c = (u * 4 + w) * 64 + l;
            int row = c & 127, kc = c >> 7;
            gload16(Bt + (size_t)(n0 + row) * K + k0 + kc * 8,
                    &Bs[buf][(u * 4 + w) * 512]);
        }
    };

    stage(0, kbeg);
    int cur = 0;
    for (int t = 0; t < nt; ++t) {
        if (t + 1 < nt) {
            stage(cur ^ 1, kbeg + (t + 1) * 32);
            if constexpr (TM == 128) asm volatile("s_waitcnt vmcnt(4)" ::: "memory");
            else                     asm volatile("s_waitcnt vmcnt(3)" ::: "memory");
        } else {
            asm volatile("s_waitcnt vmcnt(0)" ::: "memory");
        }
        __builtin_amdgcn_s_barrier();

        s16x8 af[MF], bfr[4];
        #pragma unroll
        for (int mf = 0; mf < MF; ++mf)
            af[mf] = *(const s16x8*)&As[cur][(lg * TM + wr + mf * 16 + lm) * 8];
        #pragma unroll
        for (int nf = 0; nf < 4; ++nf)
            bfr[nf] = *(const s16x8*)&Bs[cur][(lg * 128 + wc + nf * 16 + lm) * 8];
        #pragma unroll
        for (int mf = 0; mf < MF; ++mf)
            #pragma unroll
            for (int nf = 0; nf < 4; ++nf)
                acc[mf][nf] = __builtin_amdgcn_mfma_f32_16x16x32_bf16(
                    af[mf], bfr[nf], acc[mf][nf], 0, 0, 0);

        __builtin_amdgcn_s_barrier();
        cur ^= 1;
    }

    float* Cf = (float*)Cout + (size_t)blockIdx.z * zstride;
    #pragma unroll
    for (int mf = 0; mf < MF; ++mf) {
        #pragma unroll
        for (int nf = 0; nf < 4; ++nf) {
            #pragma unroll
            for (int rr = 0; rr < 4; ++rr) {
                int row = m0 + wr + mf * 16 + lg * 4 + rr;
                int col = n0 + wc + nf * 16 + lm;
                float v = acc[mf][nf][rr];
                if (EPI == 1 || (EPI == 2 && blockIdx.z == 0)) v += bias[col];
                if (EPI == 1) {
                    float targ = 0.7978845608028654f * (v + 0.044715f * v * v * v);
                    v = 0.5f * v * (1.0f + tanhf(targ));
                }
                if (EPI == 0 || EPI == 2) {
                    Cf[(size_t)row * N + col] = v;
                } else if (EPI == 1) {
                    ((us*)Cout)[(size_t)row * N + col] = f2bf(v);
                } else if (EPI == 3) {
                    int nn = col >> 6, dd = col & 63, bb = row & 1;
                    ((us*)Cout)[(((size_t)(bb * 16 + nn)) * (size_t)(M >> 1) + (row >> 1)) * 64 + dd] = f2bf(v);
                } else if (EPI == 4) {
                    int which = col >> 10;   // 0 = q (h rows only), 1 = k
                    int nn = (col >> 6) & 15, dd = col & 63, bb = row & 1;
                    us val = f2bf(v);
                    if (which == 0) {
                        if (row >= 2048)
                            ((us*)Cout)[(((size_t)(bb * 16 + nn)) * 1024 + ((row - 2048) >> 1)) * 64 + dd] = val;
                    } else {
                        ((us*)Cout + 2097152)[(((size_t)(bb * 16 + nn)) * 2048 + (row >> 1)) * 64 + dd] = val;
                    }
                } else {  // EPI 5: V^T — row = nd index, col = cat row
                    int nn = row >> 6, dd = row & 63, bb = col & 1, j = col >> 1;
                    ((us*)Cout)[(((size_t)(bb * 16 + nn)) * 64 + dd) * 2048 + j] = f2bf(v);
                }
            }
        }
    }
}

// ---------------- Qx features (+ fused ks extraction) -----------------------
__global__ __launch_bounds__(256) void eqx_k(
    const us* __restrict__ qb, const float* __restrict__ rsb,
    const float* __restrict__ se, const float* __restrict__ seg,
    float* __restrict__ Qx, us* __restrict__ ksb)
{
    if (blockIdx.x < 16) {
        int t = blockIdx.x * 256 + threadIdx.x;
        int bb = t >> 11, j = t & 2047;
        ksb[t] = f2bf(seg[(size_t)j * 4 + bb * 2 + 1]);
    }
    int task = blockIdx.x * 4 + (threadIdx.x >> 6);
    int l = threadIdx.x & 63;
    int bn = task >> 10, i = task & 1023;
    int b = bn >> 4, n = bn & 15;
    float q = bf2f(qb[((size_t)bn * QLEN + i) * DH + l]) + rsb[n * DH + l];
    float e0 = q * se[(0 * NH + n) * DH + l];
    float e1 = q * se[(1 * NH + n) * DH + l];
    #pragma unroll
    for (int off = 32; off > 0; off >>= 1) {
        e0 += __shfl_xor(e0, off);
        e1 += __shfl_xor(e1, off);
    }
    if (l == 0) {
        float qsI = seg[(size_t)i * 8192 + b * 2 + 1];
        float qs0 = seg[b * 2 + 1];
        float qs = (qsI != qs0) ? 1.f : 0.f;
        float ed = e1 - e0;
        Qx[((size_t)bn * QLEN + i) * 2 + 0] = e0 + qs * ed;
        Qx[((size_t)bn * QLEN + i) * 2 + 1] = ed * (1.f - 2.f * qs);
    }
}

// ---------------- flash attention: K/V in registers, KR dbuf LDS ------------
// grid (16,32) swizzled so each XCD owns 4 bn panels. One barrier per tile.
__global__ __launch_bounds__(256) void attn4_k(
    const us* __restrict__ qb, const us* __restrict__ kb, const us* __restrict__ vtb,
    const us* __restrict__ krb, const us* __restrict__ ksb, const float* __restrict__ Qx,
    const float* __restrict__ rwb, const float* __restrict__ rrb,
    us* __restrict__ av)
{
    __shared__ us KR_lds[2][128 * 64];
    __shared__ float G_lds[4 * 80 * 20];
    __shared__ us P_lds[4 * 16 * 64];
    __shared__ us KS_lds[2048];

    const int tid = threadIdx.x;
    const int w = tid >> 6, l = tid & 63;
    const int lm = l & 15, lg = l >> 4;
    int lin = blockIdx.y * gridDim.x + blockIdx.x;     // nwg = 512
    int swz = (lin & 7) * 64 + (lin >> 3);
    const int i0 = (swz & 15) * 64;
    const int bn = swz >> 4;
    const int b = bn >> 4, n = bn & 15;
    const int i = i0 + w * 16 + lm;

    const float SC = 0.125f * 1.44269504088896340736f;  // scale * log2(e)

    const us* kbase = kb + (size_t)bn * KLEN * DH;
    const us* vbase = vtb + (size_t)bn * DH * KLEN;

    // hoisted Q fragments, prescaled into exp2 domain
    s16x8 qwf[2], qrf[2], qxf;
    {
        const us* qrow = qb + ((size_t)bn * QLEN + i) * DH;
        #pragma unroll
        for (int ks = 0; ks < 2; ++ks) {
            s16x8 v = *(const s16x8*)(qrow + ks * 32 + lg * 8);
            #pragma unroll
            for (int e = 0; e < 8; ++e) {
                int d = ks * 32 + lg * 8 + e;
                float f = bf2f((us)v[e]);
                qwf[ks][e] = (short)f2bf((f + rwb[n * DH + d]) * SC);
                qrf[ks][e] = (short)f2bf((f + rrb[n * DH + d]) * SC);
            }
        }
        #pragma unroll
        for (int e = 0; e < 8; ++e) qxf[e] = 0;
        if (lg == 0) {
            qxf[0] = (short)f2bf(Qx[((size_t)bn * QLEN + i) * 2 + 0] * SC);
            qxf[1] = (short)f2bf(Qx[((size_t)bn * QLEN + i) * 2 + 1] * SC);
        }
    }

    auto loadK = [&](s16x8 (&kf)[4][2], int j0) {
        #pragma unroll
        for (int f = 0; f < 4; ++f)
            #pragma unroll
            for (int ks = 0; ks < 2; ++ks)
                kf[f][ks] = *(const s16x8*)(kbase + (size_t)(j0 + f * 16 + lm) * DH + ks * 32 + lg * 8);
    };
    auto stageKR = [&](int buf, int j0) {
        const int ur0 = QLEN - i0 - 63 + j0;
        #pragma unroll
        for (int u = 0; u < 4; ++u) {
            int c = (w * 4 + u) * 64 + l;
            int row = c >> 3, ch = c & 7;
            gload16(krb + ((size_t)bn * RLEN + ur0 + row) * DH + ((ch ^ (row & 7)) * 8),
                    &KR_lds[buf][(w * 4 + u) * 512]);
        }
    };

    int njt = ((i0 + 63 + MLEN) >> 6) + 1;
    if (njt > 32) njt = 32;

    // prologue
    gload16(ksb + b * KLEN + (w * 64 + l) * 8, &KS_lds[w * 512]);
    stageKR(0, 0);
    s16x8 kfA[4][2], kfB[4][2];
    loadK(kfA, 0);

    f32x4 of[4] = {{0,0,0,0},{0,0,0,0},{0,0,0,0},{0,0,0,0}};
    float M = -3.0e38f, L = 0.f;
    float* gw = &G_lds[w * 1600];
    us* pw = &P_lds[w * 1024];
    int cur = 0;

    auto computeTile = [&](int j0, s16x8 (&kf)[4][2]) {
        // V^T fragments for this tile (consumed at end -> latency covered)
        s16x8 vf[4][2];
        #pragma unroll
        for (int df = 0; df < 4; ++df)
            #pragma unroll
            for (int ks = 0; ks < 2; ++ks)
                vf[df][ks] = *(const s16x8*)(vbase + (size_t)(df * 16 + lm) * KLEN + j0 + ks * 32 + lg * 8);

        __builtin_amdgcn_s_setprio(1);
        // bd: banded G^T = KR_band x Qr^T (KR from LDS, just published)
        const int woff = 48 - w * 16;
        #pragma unroll
        for (int pf = 0; pf < 5; ++pf) {
            f32x4 g = {0, 0, 0, 0};
            int row = woff + pf * 16 + lm;
            #pragma unroll
            for (int ks = 0; ks < 2; ++ks) {
                s16x8 a = *(const s16x8*)&KR_lds[cur][row * 64 + (((ks * 64 + lg * 16) ^ ((row & 7) << 4)) >> 1)];
                g = __builtin_amdgcn_mfma_f32_16x16x32_bf16(a, qrf[ks], g, 0, 0, 0);
            }
            #pragma unroll
            for (int rr = 0; rr < 4; ++rr)
                gw[(pf * 16 + lg * 4 + rr) * 20 + lm] = g[rr];
        }
        // ac + ef (K from registers)
        f32x4 sf[4];
        #pragma unroll
        for (int f = 0; f < 4; ++f) {
            f32x4 cfr = {0, 0, 0, 0};
            cfr = __builtin_amdgcn_mfma_f32_16x16x32_bf16(kf[f][0], qwf[0], cfr, 0, 0, 0);
            cfr = __builtin_amdgcn_mfma_f32_16x16x32_bf16(kf[f][1], qwf[1], cfr, 0, 0, 0);
            s16x8 aext;
            #pragma unroll
            for (int e = 0; e < 8; ++e) aext[e] = 0;
            if (lg == 0) {
                aext[0] = (short)0x3F80;
                aext[1] = (short)KS_lds[j0 + f * 16 + lm];
            }
            cfr = __builtin_amdgcn_mfma_f32_16x16x32_bf16(aext, qxf, cfr, 0, 0, 0);
            sf[f] = cfr;
        }
        __builtin_amdgcn_s_setprio(0);

        // combine + mask + online softmax (exp2 domain)
        float sv[16];
        #pragma unroll
        for (int f = 0; f < 4; ++f)
            #pragma unroll
            for (int rr = 0; rr < 4; ++rr) {
                int jl = f * 16 + lg * 4 + rr;
                sv[f * 4 + rr] = sf[f][rr] + gw[(jl + 15 - lm) * 20 + lm];
            }
        if (j0 + 63 > i0 + w * 16 + MLEN) {
            #pragma unroll
            for (int f = 0; f < 4; ++f)
                #pragma unroll
                for (int rr = 0; rr < 4; ++rr) {
                    int jl = f * 16 + lg * 4 + rr;
                    if (j0 + jl > i + MLEN) sv[f * 4 + rr] = -1.0e30f;
                }
        }
        float tmax = sv[0];
        #pragma unroll
        for (int u = 1; u < 16; ++u) tmax = fmaxf(tmax, sv[u]);
        tmax = fmaxf(tmax, __shfl_xor(tmax, 16));
        tmax = fmaxf(tmax, __shfl_xor(tmax, 32));
        float Mnew = fmaxf(M, tmax);
        float scale;
        asm("v_exp_f32 %0, %1" : "=v"(scale) : "v"(M - Mnew));
        float psum = 0.f;
        unsigned int pk[8];
        #pragma unroll
        for (int f = 0; f < 4; ++f) {
            #pragma unroll
            for (int rp = 0; rp < 2; ++rp) {
                float p0, p1;
                asm("v_exp_f32 %0, %1" : "=v"(p0) : "v"(sv[f * 4 + rp * 2] - Mnew));
                asm("v_exp_f32 %0, %1" : "=v"(p1) : "v"(sv[f * 4 + rp * 2 + 1] - Mnew));
                psum += p0 + p1;
                unsigned int pkv;
                asm("v_cvt_pk_bf16_f32 %0, %1, %2" : "=v"(pkv) : "v"(p0), "v"(p1));
                pk[f * 2 + rp] = pkv;
            }
        }
        psum += __shfl_xor(psum, 16);
        psum += __shfl_xor(psum, 32);
        L = L * scale + psum;
        M = Mnew;
        float rs4[4];
        #pragma unroll
        for (int rr = 0; rr < 4; ++rr)
            rs4[rr] = __shfl(scale, (l & 48) | (lg * 4 + rr));
        #pragma unroll
        for (int df = 0; df < 4; ++df)
            #pragma unroll
            for (int rr = 0; rr < 4; ++rr)
                of[df][rr] *= rs4[rr];
        // P^T to per-wave LDS (same-wave producer/consumer; compiler-tracked)
        #pragma unroll
        for (int f = 0; f < 4; ++f) {
            #pragma unroll
            for (int rp = 0; rp < 2; ++rp) {
                int jl2 = f * 16 + lg * 4 + rp * 2;
                *(unsigned int*)&pw[lm * 64 + (((jl2 * 2) ^ ((lm & 7) << 4)) >> 1)] = pk[f * 2 + rp];
            }
        }
        // PV (V from registers)
        __builtin_amdgcn_s_setprio(1);
        #pragma unroll
        for (int ks = 0; ks < 2; ++ks) {
            s16x8 pa = *(const s16x8*)&pw[lm * 64 + (((ks * 64 + lg * 16) ^ ((lm & 7) << 4)) >> 1)];
            #pragma unroll
            for (int df = 0; df < 4; ++df)
                of[df] = __builtin_amdgcn_mfma_f32_16x16x32_bf16(pa, vf[df][ks], of[df], 0, 0, 0);
        }
        __builtin_amdgcn_s_setprio(0);
    };

    for (int jt = 0; jt < njt; ++jt) {
        const int j0 = jt * 64;
        asm volatile("s_waitcnt vmcnt(0)" ::: "memory");   // KR(t)+K(t) arrived
        __builtin_amdgcn_s_barrier();                      // publish KR(t)
        asm volatile("" ::: "memory");
        const bool hn = (jt + 1 < njt);
        if ((jt & 1) == 0) {
            if (hn) { loadK(kfB, j0 + 64); stageKR(cur ^ 1, j0 + 64); }
            computeTile(j0, kfA);
        } else {
            if (hn) { loadK(kfA, j0 + 64); stageKR(cur ^ 1, j0 + 64); }
            computeTile(j0, kfB);
        }
        cur ^= 1;
    }

    float rl4[4];
    #pragma unroll
    for (int rr = 0; rr < 4; ++rr)
        rl4[rr] = __shfl(L, (l & 48) | (lg * 4 + rr));
    #pragma unroll
    for (int df = 0; df < 4; ++df) {
        #pragma unroll
        for (int rr = 0; rr < 4; ++rr) {
            int m2 = lg * 4 + rr;
            int d = df * 16 + lm;
            int irow = i0 + w * 16 + m2;
            av[((size_t)irow * 2 + b) * DM + n * DH + d] = f2bf(of[df][rr] / rl4[rr]);
        }
    }
}

// ---------------- residual + layer-norm (optional 2-partial sum) ------------
template<bool SUM2, bool RESBF, bool OUTBF>
__global__ __launch_bounds__(256) void ln_k(
    const float* __restrict__ a, const float* __restrict__ a2,
    const void* __restrict__ resid,
    const float* __restrict__ g, const float* __restrict__ bb,
    void* __restrict__ out)
{
    __shared__ float xs[DM];
    __shared__ float red[5];
    const int r = blockIdx.x;
    const int t = threadIdx.x;
    float lsum = 0.f;
    #pragma unroll
    for (int u = 0; u < 4; ++u) {
        int hdx = t + 256 * u;
        float rv = RESBF ? bf2f(((const us*)resid)[(size_t)r * DM + hdx])
                         : ((const float*)resid)[(size_t)r * DM + hdx];
        float x = a[(size_t)r * DM + hdx] + rv;
        if (SUM2) x += a2[(size_t)r * DM + hdx];
        xs[hdx] = x;
        lsum += x;
    }
    float m = block_reduce<false>(lsum, red, t) * (1.0f / DM);
    float lv = 0.f;
    #pragma unroll
    for (int u = 0; u < 4; ++u) {
        int hdx = t + 256 * u;
        float dd = xs[hdx] - m;
        lv += dd * dd;
    }
    float var = block_reduce<false>(lv, red, t) * (1.0f / DM);
    float rs = rsqrtf(var + 1e-12f);
    #pragma unroll
    for (int u = 0; u < 4; ++u) {
        int hdx = t + 256 * u;
        float y = (xs[hdx] - m) * rs * g[hdx] + bb[hdx];
        if (OUTBF) ((us*)out)[(size_t)r * DM + hdx] = f2bf(y);
        else       ((float*)out)[(size_t)r * DM + hdx] = y;
    }
}

// ---------------- launch -----------------------------------------------------
extern "C" void kernel_launch(void* const* d_in, const int* in_sizes, int n_in,
                              void* d_out, int out_size, void* d_ws, size_t ws_size,
                              hipStream_t stream) {
    const float* h         = (const float*)d_in[0];
    const float* mems      = (const float*)d_in[1];
    const float* r         = (const float*)d_in[2];
    const float* seg_mat   = (const float*)d_in[3];
    const float* wq        = (const float*)d_in[5];
    const float* wk        = (const float*)d_in[6];
    const float* wv        = (const float*)d_in[7];
    const float* wo        = (const float*)d_in[8];
    const float* wr        = (const float*)d_in[9];
    const float* rwb       = (const float*)d_in[10];
    const float* rrb       = (const float*)d_in[11];
    const float* rsb       = (const float*)d_in[12];
    const float* seg_embed = (const float*)d_in[13];
    const float* ln_g      = (const float*)d_in[14];
    const float* ln_b      = (const float*)d_in[15];
    const float* w1        = (const float*)d_in[16];
    const float* b1        = (const float*)d_in[17];
    const float* w2        = (const float*)d_in[18];
    const float* b2        = (const float*)d_in[19];
    const float* lf_g      = (const float*)d_in[20];
    const float* lf_b      = (const float*)d_in[21];
    float* out = (float*)d_out;
    char* W = (char*)d_ws;
    const size_t MB = 1ull << 20;

    us*    cat_bf = (us*)(W);                 // [0,8)
    us*    r_bf   = (us*)(W + 8  * MB);       // [8,20)
    us*    wqk_t  = (us*)(W + 20 * MB);       // [20,24)
    us*    wv_t   = (us*)(W + 24 * MB);       // [24,26)
    us*    wr_t   = (us*)(W + 26 * MB);       // [26,28)
    us*    wo_b   = (us*)(W + 28 * MB);       // [28,30)
    us*    w1_t   = (us*)(W + 30 * MB);       // [30,38)
    us*    w2_t   = (us*)(W + 38 * MB);       // [38,46)
    us*    q_bf   = (us*)(W + 46 * MB);       // [46,50)
    us*    k_bf   = q_bf + 2097152;           // [50,58)
    us*    vt_bf  = (us*)(W + 58 * MB);       // [58,66)  [32][64][2048]
    us*    kr_bf  = (us*)(W + 66 * MB);       // [66,78)
    us*    av_bf  = (us*)(W + 78 * MB);       // [78,82)
    float* Qx     = (float*)(W + 82 * MB);
    us*    ks_bf  = (us*)(W + 82 * MB + 512 * 1024);
    us*    oh_bf  = (us*)(W + 83 * MB);       // [83,87)
    float* ao     = (float*)(W + 8 * MB);     // overlay [8,24): r_bf/wqk dead
    us*    ff1_bf = (us*)(W + 46 * MB);       // overlay [46,62): q/k dead
    float* ff2    = (float*)(W + 62 * MB);    // overlay [62,78): vt tail/kr dead

    dim3 blk(256);
    prep_k<<<dim3(8704), blk, 0, stream>>>(mems, h, r, wo, wq, wk, wv, wr, w1, w2,
                                           cat_bf, r_bf, wo_b, wqk_t, wv_t, wr_t, w1_t, w2_t);
    gemm2<128, 4><<<dim3(16, 32), blk, 0, stream>>>(cat_bf, wqk_t, nullptr, q_bf, 4096, 2048, 1024, 1024, 0);
    gemm2<128, 5><<<dim3(32, 8), blk, 0, stream>>>(wv_t, cat_bf, nullptr, vt_bf, 1024, 4096, 1024, 1024, 0);
    gemm2<128, 3><<<dim3(8, 48), blk, 0, stream>>>(r_bf, wr_t, nullptr, kr_bf, 6144, 1024, 1024, 1024, 0);
    eqx_k<<<dim3(8192), blk, 0, stream>>>(q_bf, rsb, seg_embed, seg_mat, Qx, ks_bf);
    attn4_k<<<dim3(16, 32), blk, 0, stream>>>(q_bf, k_bf, vt_bf, kr_bf, ks_bf, Qx, rwb, rrb, av_bf);
    gemm2<64, 0><<<dim3(8, 32, 2), blk, 0, stream>>>(av_bf, wo_b, nullptr, ao, 2048, 1024, 1024, 512, 2097152);
    ln_k<true, false, true><<<dim3(2048), blk, 0, stream>>>(ao, ao + 2097152, h, ln_g, ln_b, oh_bf);
    gemm2<128, 1><<<dim3(32, 16), blk, 0, stream>>>(oh_bf, w1_t, b1, ff1_bf, 2048, 4096, 1024, 1024, 0);
    gemm2<64, 2><<<dim3(8, 32, 2), blk, 0, stream>>>(ff1_bf, w2_t, b2, ff2, 2048, 1024, 4096, 2048, 2097152);
    ln_k<true, true, false><<<dim3(2048), blk, 0, stream>>>(ff2, ff2 + 2097152, oh_bf, lf_g, lf_b, out);
}

// Round 7
// 342.564 us; speedup vs baseline: 1.4382x; 1.4382x over previous
//
#include <hip/hip_runtime.h>
#include <hip/hip_bf16.h>

// XLNet rel-attn layer + FFN. Round 7: attention K/V in fragment-major global
// layout (coalesced register loads, L1-resident), KR dbuf LDS, ONE barrier
// per tile. GEMM epilogues emit the fragment layouts directly.
// QLEN=1024 MLEN=1024 BSZ=2 DM=1024 NH=16 DH=64 DI=4096 KLEN=2048 RLEN=3072.

#define QLEN 1024
#define MLEN 1024
#define DM 1024
#define NH 16
#define DH 64
#define DI 4096
#define KLEN 2048
#define RLEN 3072

typedef __attribute__((ext_vector_type(8))) short s16x8;
typedef __attribute__((ext_vector_type(4))) float f32x4;
typedef unsigned short us;

__device__ __forceinline__ float bf2f(us u) {
    union { unsigned int i; float f; } x; x.i = ((unsigned int)u) << 16; return x.f;
}
__device__ __forceinline__ us f2bf(float f) {
    union { float f; unsigned int i; } x; x.f = f;
    return (us)((x.i + 0x7fffu + ((x.i >> 16) & 1u)) >> 16);
}
__device__ __forceinline__ void gload16(const void* g, void* lds) {
    __builtin_amdgcn_global_load_lds(
        (const __attribute__((address_space(1))) unsigned int*)g,
        (__attribute__((address_space(3))) unsigned int*)lds, 16, 0, 0);
}

// ---------------- block reduction (wave=64, 4 waves/block) ------------------
template<bool ISMAX>
__device__ __forceinline__ float block_reduce(float v, float* red, int t) {
    #pragma unroll
    for (int off = 32; off > 0; off >>= 1) {
        float o = __shfl_down(v, off);
        v = ISMAX ? fmaxf(v, o) : (v + o);
    }
    if ((t & 63) == 0) red[t >> 6] = v;
    __syncthreads();
    if (t == 0) {
        float s = red[0];
        #pragma unroll
        for (int w = 1; w < 4; ++w) s = ISMAX ? fmaxf(s, red[w]) : (s + red[w]);
        red[4] = s;
    }
    __syncthreads();
    return red[4];
}

// ---------------- unified prep: all fp32->bf16 converts + transposes --------
__global__ __launch_bounds__(256) void prep_k(
    const float* __restrict__ mems, const float* __restrict__ h,
    const float* __restrict__ r, const float* __restrict__ wo,
    const float* __restrict__ wq, const float* __restrict__ wk,
    const float* __restrict__ wv, const float* __restrict__ wr,
    const float* __restrict__ w1, const float* __restrict__ w2,
    us* __restrict__ cat_bf, us* __restrict__ r_bf, us* __restrict__ wo_b,
    us* __restrict__ wqk_t, us* __restrict__ wv_t, us* __restrict__ wr_t,
    us* __restrict__ w1_t, us* __restrict__ w2_t)
{
    __shared__ us tbuf[64][65];
    int bid = blockIdx.x;
    const int tid = threadIdx.x;
    if (bid < 5632) {
        int t = bid * 256 + tid;
        const float* src; us* dst; int off;
        if (t < 262144)       { src = mems; dst = cat_bf;           off = t; }
        else if (t < 524288)  { src = h;    dst = cat_bf + 2097152; off = t - 262144; }
        else if (t < 1310720) { src = r;    dst = r_bf;             off = t - 524288; }
        else                  { src = wo;   dst = wo_b;             off = t - 1310720; }
        const float4* p = (const float4*)src + 2 * (size_t)off;
        float4 a = p[0], b = p[1];
        us o[8] = { f2bf(a.x), f2bf(a.y), f2bf(a.z), f2bf(a.w),
                    f2bf(b.x), f2bf(b.y), f2bf(b.z), f2bf(b.w) };
        *((uint4*)dst + off) = *(const uint4*)o;
        return;
    }
    bid -= 5632;
    const float* in; us* out; int R, C, c0, r0;
    if (bid < 1024) {
        int z = bid >> 8, u = bid & 255;
        in  = (z == 0) ? wq : (z == 1) ? wk : (z == 2) ? wv : wr;
        out = (z == 0) ? wqk_t : (z == 1) ? (wqk_t + 1048576) : (z == 2) ? wv_t : wr_t;
        R = 1024; C = 1024; c0 = (u & 15) * 64; r0 = (u >> 4) * 64;
    } else if (bid < 2048) {
        int u = bid - 1024;
        in = w1; out = w1_t; R = 1024; C = 4096;
        c0 = (u & 63) * 64; r0 = (u >> 6) * 64;
    } else {
        int u = bid - 2048;
        in = w2; out = w2_t; R = 4096; C = 1024;
        c0 = (u & 15) * 64; r0 = (u >> 4) * 64;
    }
    #pragma unroll
    for (int u = 0; u < 16; ++u) {
        int idx = tid + 256 * u;
        int rr = idx >> 6, cc = idx & 63;
        tbuf[cc][rr] = f2bf(in[(size_t)(r0 + rr) * C + c0 + cc]);
    }
    __syncthreads();
    #pragma unroll
    for (int u = 0; u < 16; ++u) {
        int idx = tid + 256 * u;
        int rr = idx >> 6, cc = idx & 63;
        out[(size_t)(c0 + rr) * R + r0 + cc] = tbuf[rr][cc];
    }
}

// ---------------- pipelined bf16 MFMA GEMM ----------------------------------
// EPI: 0 f32; 1 bias+gelu->bf16; 2 bias(z0)->f32; 3 bf16 scatter [bn][seq][64];
//      4 q scatter + K fragment-major; 5 V^T fragment-major.
template<int TM, int EPI>
__global__ __launch_bounds__(256) void gemm2(
    const us* __restrict__ A, const us* __restrict__ Bt,
    const float* __restrict__ bias, void* __restrict__ Cout,
    int M, int N, int K, int kchunk, size_t zstride)
{
    constexpr int MF = TM / 32;
    constexpr int AISS = TM / 64;
    __shared__ us As[2][TM * 32];
    __shared__ us Bs[2][128 * 32];

    const int tid = threadIdx.x;
    const int w = tid >> 6, l = tid & 63;
    const int lm = l & 15, lg = l >> 4;

    int lin = blockIdx.y * gridDim.x + blockIdx.x;
    int nwg = gridDim.x * gridDim.y;
    int swz = (lin & 7) * (nwg >> 3) + (lin >> 3);
    int bx = swz % gridDim.x, by = swz / gridDim.x;
    const int m0 = by * TM, n0 = bx * 128;
    const int wr = (w >> 1) * (TM / 2), wc = (w & 1) * 64;
    const int kbeg = blockIdx.z * kchunk;
    const int nt = kchunk / 32;

    f32x4 acc[MF][4] = {};

    auto stage = [&](int buf, int k0) {
        #pragma unroll
        for (int u = 0; u < AISS; ++u) {
            int c = (u * 4 + w) * 64 + l;
            int row = c & (TM - 1), kc = c >> (TM == 128 ? 7 : 6);
            gload16(A + (size_t)(m0 + row) * K + k0 + kc * 8,
                    &As[buf][(u * 4 + w) * 512]);
        }
        #pragma unroll
        for (int u = 0; u < 2; ++u) {
            int c = (u * 4 + w) * 64 + l;
            int row = c & 127, kc = c >> 7;
            gload16(Bt + (size_t)(n0 + row) * K + k0 + kc * 8,
                    &Bs[buf][(u * 4 + w) * 512]);
        }
    };

    stage(0, kbeg);
    int cur = 0;
    for (int t = 0; t < nt; ++t) {
        if (t + 1 < nt) {
            stage(cur ^ 1, kbeg + (t + 1) * 32);
            if constexpr (TM == 128) asm volatile("s_waitcnt vmcnt(4)" ::: "memory");
            else                     asm volatile("s_waitcnt vmcnt(3)" ::: "memory");
        } else {
            asm volatile("s_waitcnt vmcnt(0)" ::: "memory");
        }
        __builtin_amdgcn_s_barrier();

        s16x8 af[MF], bfr[4];
        #pragma unroll
        for (int mf = 0; mf < MF; ++mf)
            af[mf] = *(const s16x8*)&As[cur][(lg * TM + wr + mf * 16 + lm) * 8];
        #pragma unroll
        for (int nf = 0; nf < 4; ++nf)
            bfr[nf] = *(const s16x8*)&Bs[cur][(lg * 128 + wc + nf * 16 + lm) * 8];
        #pragma unroll
        for (int mf = 0; mf < MF; ++mf)
            #pragma unroll
            for (int nf = 0; nf < 4; ++nf)
                acc[mf][nf] = __builtin_amdgcn_mfma_f32_16x16x32_bf16(
                    af[mf], bfr[nf], acc[mf][nf], 0, 0, 0);

        __builtin_amdgcn_s_barrier();
        cur ^= 1;
    }

    float* Cf = (float*)Cout + (size_t)blockIdx.z * zstride;
    #pragma unroll
    for (int mf = 0; mf < MF; ++mf) {
        #pragma unroll
        for (int nf = 0; nf < 4; ++nf) {
            #pragma unroll
            for (int rr = 0; rr < 4; ++rr) {
                int row = m0 + wr + mf * 16 + lg * 4 + rr;
                int col = n0 + wc + nf * 16 + lm;
                float v = acc[mf][nf][rr];
                if (EPI == 1 || (EPI == 2 && blockIdx.z == 0)) v += bias[col];
                if (EPI == 1) {
                    float targ = 0.7978845608028654f * (v + 0.044715f * v * v * v);
                    v = 0.5f * v * (1.0f + tanhf(targ));
                }
                if (EPI == 0 || EPI == 2) {
                    Cf[(size_t)row * N + col] = v;
                } else if (EPI == 1) {
                    ((us*)Cout)[(size_t)row * N + col] = f2bf(v);
                } else if (EPI == 3) {
                    int nn = col >> 6, dd = col & 63, bb = row & 1;
                    ((us*)Cout)[(((size_t)(bb * 16 + nn)) * (size_t)(M >> 1) + (row >> 1)) * 64 + dd] = f2bf(v);
                } else if (EPI == 4) {
                    int which = col >> 10;   // 0 = q (h rows only), 1 = K fragments
                    int nn = (col >> 6) & 15, dd = col & 63, bb = row & 1;
                    us val = f2bf(v);
                    if (which == 0) {
                        if (row >= 2048)
                            ((us*)Cout)[(((size_t)(bb * 16 + nn)) * 1024 + ((row - 2048) >> 1)) * 64 + dd] = val;
                    } else {
                        // K fragment-major: [bn][jt][f][ks][lane(lg,lm)][e]
                        int j = row >> 1;
                        int jt = j >> 6, ff = (j >> 4) & 3, lmw = j & 15;
                        int ks2 = dd >> 5, lg2 = (dd >> 3) & 3, e2 = dd & 7;
                        us* kf = (us*)Cout + 2097152;
                        kf[((((size_t)(bb * 16 + nn) * 32 + jt) * 8 + ff * 2 + ks2) * 64
                            + lg2 * 16 + lmw) * 8 + e2] = val;
                    }
                } else {  // EPI 5: V^T fragment-major [bn][jt][df][ks][lane][e]
                    int nn = row >> 6, dd2 = row & 63, bb = col & 1, j = col >> 1;
                    int df = dd2 >> 4, lmw = dd2 & 15;
                    int jt = j >> 6, ks2 = (j >> 5) & 1, lg2 = (j >> 3) & 3, e2 = j & 7;
                    ((us*)Cout)[((((size_t)(bb * 16 + nn) * 32 + jt) * 8 + df * 2 + ks2) * 64
                                 + lg2 * 16 + lmw) * 8 + e2] = f2bf(v);
                }
            }
        }
    }
}

// ---------------- Qx features (+ fused ks extraction) -----------------------
__global__ __launch_bounds__(256) void eqx_k(
    const us* __restrict__ qb, const float* __restrict__ rsb,
    const float* __restrict__ se, const float* __restrict__ seg,
    float* __restrict__ Qx, us* __restrict__ ksb)
{
    if (blockIdx.x < 16) {
        int t = blockIdx.x * 256 + threadIdx.x;
        int bb = t >> 11, j = t & 2047;
        ksb[t] = f2bf(seg[(size_t)j * 4 + bb * 2 + 1]);
    }
    int task = blockIdx.x * 4 + (threadIdx.x >> 6);
    int l = threadIdx.x & 63;
    int bn = task >> 10, i = task & 1023;
    int b = bn >> 4, n = bn & 15;
    float q = bf2f(qb[((size_t)bn * QLEN + i) * DH + l]) + rsb[n * DH + l];
    float e0 = q * se[(0 * NH + n) * DH + l];
    float e1 = q * se[(1 * NH + n) * DH + l];
    #pragma unroll
    for (int off = 32; off > 0; off >>= 1) {
        e0 += __shfl_xor(e0, off);
        e1 += __shfl_xor(e1, off);
    }
    if (l == 0) {
        float qsI = seg[(size_t)i * 8192 + b * 2 + 1];
        float qs0 = seg[b * 2 + 1];
        float qs = (qsI != qs0) ? 1.f : 0.f;
        float ed = e1 - e0;
        Qx[((size_t)bn * QLEN + i) * 2 + 0] = e0 + qs * ed;
        Qx[((size_t)bn * QLEN + i) * 2 + 1] = ed * (1.f - 2.f * qs);
    }
}

// ---------------- flash attention: fragment-major K/V regs, KR dbuf ---------
// One barrier per tile. LDS = 2x16K KR + 25.6K G + 8K P + 4K KS = 69.6 KB.
__global__ __launch_bounds__(256) void attn5_k(
    const us* __restrict__ qb, const us* __restrict__ kfr, const us* __restrict__ vfr,
    const us* __restrict__ krb, const us* __restrict__ ksb, const float* __restrict__ Qx,
    const float* __restrict__ rwb, const float* __restrict__ rrb,
    us* __restrict__ av)
{
    __shared__ us KR_lds[2][128 * 64];
    __shared__ float G_lds[4 * 80 * 20];
    __shared__ us P_lds[4 * 16 * 64];
    __shared__ us KS_lds[2048];

    const int tid = threadIdx.x;
    const int w = tid >> 6, l = tid & 63;
    const int lm = l & 15, lg = l >> 4;
    int lin = blockIdx.y * gridDim.x + blockIdx.x;     // nwg = 512
    int swz = (lin & 7) * 64 + (lin >> 3);
    const int i0 = (swz & 15) * 64;
    const int bn = swz >> 4;
    const int b = bn >> 4, n = bn & 15;
    const int i = i0 + w * 16 + lm;

    const float SC = 0.125f * 1.44269504088896340736f;  // scale * log2(e)

    const us* kbase = kfr + (size_t)bn * 131072;  // 32 jt * 8 * 512
    const us* vbase = vfr + (size_t)bn * 131072;

    // hoisted Q fragments, prescaled into exp2 domain
    s16x8 qwf[2], qrf[2], qxf;
    {
        const us* qrow = qb + ((size_t)bn * QLEN + i) * DH;
        #pragma unroll
        for (int ks = 0; ks < 2; ++ks) {
            s16x8 v = *(const s16x8*)(qrow + ks * 32 + lg * 8);
            #pragma unroll
            for (int e = 0; e < 8; ++e) {
                int d = ks * 32 + lg * 8 + e;
                float f = bf2f((us)v[e]);
                qwf[ks][e] = (short)f2bf((f + rwb[n * DH + d]) * SC);
                qrf[ks][e] = (short)f2bf((f + rrb[n * DH + d]) * SC);
            }
        }
        #pragma unroll
        for (int e = 0; e < 8; ++e) qxf[e] = 0;
        if (lg == 0) {
            qxf[0] = (short)f2bf(Qx[((size_t)bn * QLEN + i) * 2 + 0] * SC);
            qxf[1] = (short)f2bf(Qx[((size_t)bn * QLEN + i) * 2 + 1] * SC);
        }
    }

    auto stageKR = [&](int buf, int j0) {
        const int ur0 = QLEN - i0 - 63 + j0;
        #pragma unroll
        for (int u = 0; u < 4; ++u) {
            int c = (w * 4 + u) * 64 + l;
            int row = c >> 3, ch = c & 7;
            gload16(krb + ((size_t)bn * RLEN + ur0 + row) * DH + ((ch ^ (row & 7)) * 8),
                    &KR_lds[buf][(w * 4 + u) * 512]);
        }
    };

    int njt = ((i0 + 63 + MLEN) >> 6) + 1;
    if (njt > 32) njt = 32;

    // prologue
    gload16(ksb + b * KLEN + (w * 64 + l) * 8, &KS_lds[w * 512]);
    stageKR(0, 0);

    f32x4 of[4] = {{0,0,0,0},{0,0,0,0},{0,0,0,0},{0,0,0,0}};
    float M = -3.0e38f, L = 0.f;
    float* gw = &G_lds[w * 1600];
    us* pw = &P_lds[w * 1024];
    int cur = 0;

    for (int jt = 0; jt < njt; ++jt) {
        const int j0 = jt * 64;
        asm volatile("s_waitcnt vmcnt(0)" ::: "memory");   // KR(t) landed
        __builtin_amdgcn_s_barrier();                      // publish KR(t)
        asm volatile("" ::: "memory");
        if (jt + 1 < njt) stageKR(cur ^ 1, j0 + 64);       // prefetch KR(t+1)

        // coalesced fragment loads (L1-resident; compiler-scheduled waits)
        s16x8 kf[4][2], vf[4][2];
        #pragma unroll
        for (int f = 0; f < 4; ++f) {
            #pragma unroll
            for (int ks = 0; ks < 2; ++ks) {
                kf[f][ks] = *(const s16x8*)(kbase + (size_t)(((jt * 4 + f) * 2 + ks) * 64 + l) * 8);
                vf[f][ks] = *(const s16x8*)(vbase + (size_t)(((jt * 4 + f) * 2 + ks) * 64 + l) * 8);
            }
        }

        __builtin_amdgcn_s_setprio(1);
        // bd: banded G^T = KR_band x Qr^T
        const int woff = 48 - w * 16;
        #pragma unroll
        for (int pf = 0; pf < 5; ++pf) {
            f32x4 g = {0, 0, 0, 0};
            int row = woff + pf * 16 + lm;
            #pragma unroll
            for (int ks = 0; ks < 2; ++ks) {
                s16x8 a = *(const s16x8*)&KR_lds[cur][row * 64 + (((ks * 64 + lg * 16) ^ ((row & 7) << 4)) >> 1)];
                g = __builtin_amdgcn_mfma_f32_16x16x32_bf16(a, qrf[ks], g, 0, 0, 0);
            }
            #pragma unroll
            for (int rr = 0; rr < 4; ++rr)
                gw[(pf * 16 + lg * 4 + rr) * 20 + lm] = g[rr];
        }
        // ac + ef (K from registers)
        f32x4 sf[4];
        #pragma unroll
        for (int f = 0; f < 4; ++f) {
            f32x4 cfr = {0, 0, 0, 0};
            cfr = __builtin_amdgcn_mfma_f32_16x16x32_bf16(kf[f][0], qwf[0], cfr, 0, 0, 0);
            cfr = __builtin_amdgcn_mfma_f32_16x16x32_bf16(kf[f][1], qwf[1], cfr, 0, 0, 0);
            s16x8 aext;
            #pragma unroll
            for (int e = 0; e < 8; ++e) aext[e] = 0;
            if (lg == 0) {
                aext[0] = (short)0x3F80;
                aext[1] = (short)KS_lds[j0 + f * 16 + lm];
            }
            cfr = __builtin_amdgcn_mfma_f32_16x16x32_bf16(aext, qxf, cfr, 0, 0, 0);
            sf[f] = cfr;
        }
        __builtin_amdgcn_s_setprio(0);

        // combine + mask + online softmax (exp2 domain)
        float sv[16];
        #pragma unroll
        for (int f = 0; f < 4; ++f)
            #pragma unroll
            for (int rr = 0; rr < 4; ++rr) {
                int jl = f * 16 + lg * 4 + rr;
                sv[f * 4 + rr] = sf[f][rr] + gw[(jl + 15 - lm) * 20 + lm];
            }
        if (j0 + 63 > i0 + w * 16 + MLEN) {
            #pragma unroll
            for (int f = 0; f < 4; ++f)
                #pragma unroll
                for (int rr = 0; rr < 4; ++rr) {
                    int jl = f * 16 + lg * 4 + rr;
                    if (j0 + jl > i + MLEN) sv[f * 4 + rr] = -1.0e30f;
                }
        }
        float tmax = sv[0];
        #pragma unroll
        for (int u = 1; u < 16; ++u) tmax = fmaxf(tmax, sv[u]);
        tmax = fmaxf(tmax, __shfl_xor(tmax, 16));
        tmax = fmaxf(tmax, __shfl_xor(tmax, 32));
        float Mnew = fmaxf(M, tmax);
        float scale;
        asm("v_exp_f32 %0, %1" : "=v"(scale) : "v"(M - Mnew));
        float psum = 0.f;
        unsigned int pk[8];
        #pragma unroll
        for (int f = 0; f < 4; ++f) {
            #pragma unroll
            for (int rp = 0; rp < 2; ++rp) {
                float p0, p1;
                asm("v_exp_f32 %0, %1" : "=v"(p0) : "v"(sv[f * 4 + rp * 2] - Mnew));
                asm("v_exp_f32 %0, %1" : "=v"(p1) : "v"(sv[f * 4 + rp * 2 + 1] - Mnew));
                psum += p0 + p1;
                unsigned int pkv;
                asm("v_cvt_pk_bf16_f32 %0, %1, %2" : "=v"(pkv) : "v"(p0), "v"(p1));
                pk[f * 2 + rp] = pkv;
            }
        }
        psum += __shfl_xor(psum, 16);
        psum += __shfl_xor(psum, 32);
        L = L * scale + psum;
        M = Mnew;
        float rs4[4];
        #pragma unroll
        for (int rr = 0; rr < 4; ++rr)
            rs4[rr] = __shfl(scale, (l & 48) | (lg * 4 + rr));
        #pragma unroll
        for (int df = 0; df < 4; ++df)
            #pragma unroll
            for (int rr = 0; rr < 4; ++rr)
                of[df][rr] *= rs4[rr];
        // P^T to per-wave LDS (same-wave producer/consumer)
        #pragma unroll
        for (int f = 0; f < 4; ++f) {
            #pragma unroll
            for (int rp = 0; rp < 2; ++rp) {
                int jl2 = f * 16 + lg * 4 + rp * 2;
                *(unsigned int*)&pw[lm * 64 + (((jl2 * 2) ^ ((lm & 7) << 4)) >> 1)] = pk[f * 2 + rp];
            }
        }
        // PV (V from registers)
        __builtin_amdgcn_s_setprio(1);
        #pragma unroll
        for (int ks = 0; ks < 2; ++ks) {
            s16x8 pa = *(const s16x8*)&pw[lm * 64 + (((ks * 64 + lg * 16) ^ ((lm & 7) << 4)) >> 1)];
            #pragma unroll
            for (int df = 0; df < 4; ++df)
                of[df] = __builtin_amdgcn_mfma_f32_16x16x32_bf16(pa, vf[df][ks], of[df], 0, 0, 0);
        }
        __builtin_amdgcn_s_setprio(0);
        cur ^= 1;
    }

    float rl4[4];
    #pragma unroll
    for (int rr = 0; rr < 4; ++rr)
        rl4[rr] = __shfl(L, (l & 48) | (lg * 4 + rr));
    #pragma unroll
    for (int df = 0; df < 4; ++df) {
        #pragma unroll
        for (int rr = 0; rr < 4; ++rr) {
            int m2 = lg * 4 + rr;
            int d = df * 16 + lm;
            int irow = i0 + w * 16 + m2;
            av[((size_t)irow * 2 + b) * DM + n * DH + d] = f2bf(of[df][rr] / rl4[rr]);
        }
    }
}

// ---------------- residual + layer-norm (optional 2-partial sum) ------------
template<bool SUM2, bool RESBF, bool OUTBF>
__global__ __launch_bounds__(256) void ln_k(
    const float* __restrict__ a, const float* __restrict__ a2,
    const void* __restrict__ resid,
    const float* __restrict__ g, const float* __restrict__ bb,
    void* __restrict__ out)
{
    __shared__ float xs[DM];
    __shared__ float red[5];
    const int r = blockIdx.x;
    const int t = threadIdx.x;
    float lsum = 0.f;
    #pragma unroll
    for (int u = 0; u < 4; ++u) {
        int hdx = t + 256 * u;
        float rv = RESBF ? bf2f(((const us*)resid)[(size_t)r * DM + hdx])
                         : ((const float*)resid)[(size_t)r * DM + hdx];
        float x = a[(size_t)r * DM + hdx] + rv;
        if (SUM2) x += a2[(size_t)r * DM + hdx];
        xs[hdx] = x;
        lsum += x;
    }
    float m = block_reduce<false>(lsum, red, t) * (1.0f / DM);
    float lv = 0.f;
    #pragma unroll
    for (int u = 0; u < 4; ++u) {
        int hdx = t + 256 * u;
        float dd = xs[hdx] - m;
        lv += dd * dd;
    }
    float var = block_reduce<false>(lv, red, t) * (1.0f / DM);
    float rs = rsqrtf(var + 1e-12f);
    #pragma unroll
    for (int u = 0; u < 4; ++u) {
        int hdx = t + 256 * u;
        float y = (xs[hdx] - m) * rs * g[hdx] + bb[hdx];
        if (OUTBF) ((us*)out)[(size_t)r * DM + hdx] = f2bf(y);
        else       ((float*)out)[(size_t)r * DM + hdx] = y;
    }
}

// ---------------- launch -----------------------------------------------------
extern "C" void kernel_launch(void* const* d_in, const int* in_sizes, int n_in,
                              void* d_out, int out_size, void* d_ws, size_t ws_size,
                              hipStream_t stream) {
    const float* h         = (const float*)d_in[0];
    const float* mems      = (const float*)d_in[1];
    const float* r         = (const float*)d_in[2];
    const float* seg_mat   = (const float*)d_in[3];
    const float* wq        = (const float*)d_in[5];
    const float* wk        = (const float*)d_in[6];
    const float* wv        = (const float*)d_in[7];
    const float* wo        = (const float*)d_in[8];
    const float* wr        = (const float*)d_in[9];
    const float* rwb       = (const float*)d_in[10];
    const float* rrb       = (const float*)d_in[11];
    const float* rsb       = (const float*)d_in[12];
    const float* seg_embed = (const float*)d_in[13];
    const float* ln_g      = (const float*)d_in[14];
    const float* ln_b      = (const float*)d_in[15];
    const float* w1        = (const float*)d_in[16];
    const float* b1        = (const float*)d_in[17];
    const float* w2        = (const float*)d_in[18];
    const float* b2        = (const float*)d_in[19];
    const float* lf_g      = (const float*)d_in[20];
    const float* lf_b      = (const float*)d_in[21];
    float* out = (float*)d_out;
    char* W = (char*)d_ws;
    const size_t MB = 1ull << 20;

    us*    cat_bf = (us*)(W);                 // [0,8)
    us*    r_bf   = (us*)(W + 8  * MB);       // [8,20)
    us*    wqk_t  = (us*)(W + 20 * MB);       // [20,24)
    us*    wv_t   = (us*)(W + 24 * MB);       // [24,26)
    us*    wr_t   = (us*)(W + 26 * MB);       // [26,28)
    us*    wo_b   = (us*)(W + 28 * MB);       // [28,30)
    us*    w1_t   = (us*)(W + 30 * MB);       // [30,38)
    us*    w2_t   = (us*)(W + 38 * MB);       // [38,46)
    us*    q_bf   = (us*)(W + 46 * MB);       // [46,50)
    us*    kfrag  = q_bf + 2097152;           // [50,58)  fragment-major
    us*    vfrag  = (us*)(W + 58 * MB);       // [58,66)  fragment-major
    us*    kr_bf  = (us*)(W + 66 * MB);       // [66,78)
    us*    av_bf  = (us*)(W + 78 * MB);       // [78,82)
    float* Qx     = (float*)(W + 82 * MB);
    us*    ks_bf  = (us*)(W + 82 * MB + 512 * 1024);
    us*    oh_bf  = (us*)(W + 83 * MB);       // [83,87)
    float* ao     = (float*)(W + 8 * MB);     // overlay [8,24)
    us*    ff1_bf = (us*)(W + 46 * MB);       // overlay [46,62)
    float* ff2    = (float*)(W + 62 * MB);    // overlay [62,78)

    dim3 blk(256);
    prep_k<<<dim3(8704), blk, 0, stream>>>(mems, h, r, wo, wq, wk, wv, wr, w1, w2,
                                           cat_bf, r_bf, wo_b, wqk_t, wv_t, wr_t, w1_t, w2_t);
    gemm2<128, 4><<<dim3(16, 32), blk, 0, stream>>>(cat_bf, wqk_t, nullptr, q_bf, 4096, 2048, 1024, 1024, 0);
    gemm2<128, 5><<<dim3(32, 8), blk, 0, stream>>>(wv_t, cat_bf, nullptr, vfrag, 1024, 4096, 1024, 1024, 0);
    gemm2<128, 3><<<dim3(8, 48), blk, 0, stream>>>(r_bf, wr_t, nullptr, kr_bf, 6144, 1024, 1024, 1024, 0);
    eqx_k<<<dim3(8192), blk, 0, stream>>>(q_bf, rsb, seg_embed, seg_mat, Qx, ks_bf);
    attn5_k<<<dim3(16, 32), blk, 0, stream>>>(q_bf, kfrag, vfrag, kr_bf, ks_bf, Qx, rwb, rrb, av_bf);
    gemm2<64, 0><<<dim3(8, 32, 2), blk, 0, stream>>>(av_bf, wo_b, nullptr, ao, 2048, 1024, 1024, 512, 2097152);
    ln_k<true, false, true><<<dim3(2048), blk, 0, stream>>>(ao, ao + 2097152, h, ln_g, ln_b, oh_bf);
    gemm2<128, 1><<<dim3(32, 16), blk, 0, stream>>>(oh_bf, w1_t, b1, ff1_bf, 2048, 4096, 1024, 1024, 0);
    gemm2<64, 2><<<dim3(8, 32, 2), blk, 0, stream>>>(ff1_bf, w2_t, b2, ff2, 2048, 1024, 4096, 2048, 2097152);
    ln_k<true, true, false><<<dim3(2048), blk, 0, stream>>>(ff2, ff2 + 2097152, oh_bf, lf_g, lf_b, out);
}